// Round 1
// baseline (172.014 us; speedup 1.0000x reference)
//
#include <hip/hip_runtime.h>
#include <hip/hip_bf16.h>
#include <hip/hip_fp16.h>

// out[e] = relu(z_s[row[e]]@W1_top + z_c[col[e]]@W1_bot + b1) @ W2 + b2
// u_s = z_s@W1_top + b1, u_c = z_c@W1_bot (both f16 in ws); per edge:
// out = sum_k relu(u_s[row][k]+u_c[col][k]) * W2[k] + b2.

typedef _Float16 half2v __attribute__((ext_vector_type(2)));
typedef _Float16 half8v __attribute__((ext_vector_type(8)));
typedef __fp16   fp16x2 __attribute__((ext_vector_type(2)));
typedef float    float4v __attribute__((ext_vector_type(4)));

// ---- Kernel 1: W1 [256,128] fp32 -> Wt[half][n][k] f16 (LDS transpose), W2 -> f16 ----
__global__ __launch_bounds__(256) void conv_w(const float* __restrict__ W1,
                                              const float* __restrict__ W2,
                                              _Float16* __restrict__ Wt,
                                              _Float16* __restrict__ w2h) {
    int b = blockIdx.x, t = threadIdx.x;
    if (b == 8) { if (t < 128) w2h[t] = (_Float16)W2[t]; return; }
    __shared__ _Float16 lds[32][136];
    int h = b >> 2, n0 = (b & 3) * 32;
    for (int i = 0; i < 16; ++i) {
        int idx = i * 256 + t;            // 4096 = 128k x 32n
        int k = idx >> 5, nn = idx & 31;
        lds[nn][k] = (_Float16)W1[(h * 128 + k) * 128 + n0 + nn];
    }
    __syncthreads();
    for (int j = 0; j < 2; ++j) {
        int idx = j * 256 + t;            // 512 = 32n x 16 chunks
        int nn = idx >> 4, kc = idx & 15;
        half8v v;
        #pragma unroll
        for (int q = 0; q < 8; ++q) v[q] = lds[nn][kc * 8 + q];
        *(half8v*)&Wt[((h * 128 + n0 + nn) * 128) + kc * 8] = v;
    }
}

// ---- Kernel 2: fused U_s / U_c GEMM, MFMA 16x16x32 f16, vectorized epilogue ----
// LDS layout: row n (128 rows), 16 chunks of 16B, chunk slot = ch ^ ((n>>3)&7)
// -> B-frag ds_read_b128 lands 2-way bank aliased (free).
__global__ __launch_bounds__(256) void gemm_u(
    const float* __restrict__ Zs, const float* __restrict__ Zc,
    const _Float16* __restrict__ Wt, const float* __restrict__ b1,
    _Float16* __restrict__ Us, _Float16* __restrict__ Uc,
    int Ms, int Mc, int nbs)
{
    __shared__ uint4 ldsW[2048];          // 128 x 16 chunks, swizzled, 32 KiB
    const int bid = blockIdx.x, t = threadIdx.x;

    const float* Z; _Float16* U; const _Float16* W; int M, m0, addB;
    if (bid < nbs) { Z = Zs; U = Us; M = Ms; m0 = bid * 64;         W = Wt;         addB = 1; }
    else           { Z = Zc; U = Uc; M = Mc; m0 = (bid - nbs) * 64; W = Wt + 16384; addB = 0; }

    const uint4* Wv = (const uint4*)W;    // [n][16 chunks]
    #pragma unroll
    for (int i = 0; i < 8; ++i) {
        int j = i * 256 + t;              // 2048
        int n = j >> 4, ch = j & 15;
        ldsW[n * 16 + (ch ^ ((n >> 3) & 7))] = Wv[j];
    }
    __syncthreads();

    const int wave = t >> 6, lane = t & 63, quad = lane >> 4, l16 = lane & 15;
    int mrow = m0 + wave * 16 + l16;
    int mload = mrow < M ? mrow : M - 1;  // clamp; stores guarded
    const float* zrow = Z + (long)mload * 128;

    float4v acc[8];
    #pragma unroll
    for (int nt = 0; nt < 8; ++nt) acc[nt] = (float4v)(0.0f);

    #pragma unroll
    for (int c = 0; c < 4; ++c) {
        const float4v* pa = (const float4v*)(zrow + c * 32 + quad * 8);
        float4v a0 = pa[0], a1 = pa[1];
        fp16x2 p[4];
        p[0] = __builtin_amdgcn_cvt_pkrtz(a0[0], a0[1]);
        p[1] = __builtin_amdgcn_cvt_pkrtz(a0[2], a0[3]);
        p[2] = __builtin_amdgcn_cvt_pkrtz(a1[0], a1[1]);
        p[3] = __builtin_amdgcn_cvt_pkrtz(a1[2], a1[3]);
        half8v af;
        __builtin_memcpy(&af, &p[0], 16);
        const int ch = c * 4 + quad;
        #pragma unroll
        for (int nt = 0; nt < 8; ++nt) {
            // MFMA #nt computes actual col n = l16*8 + nt at frag-col l16
            const int n = l16 * 8 + nt;
            const half8v* pb = (const half8v*)&ldsW[n * 16 + (ch ^ (l16 & 7))];
            acc[nt] = __builtin_amdgcn_mfma_f32_16x16x32_f16(af, *pb, acc[nt], 0, 0, 0);
        }
    }

    float bv[8];
    if (addB) {
        const float4v* pb1 = (const float4v*)(b1 + l16 * 8);
        float4v x0 = pb1[0], x1 = pb1[1];
        bv[0]=x0[0]; bv[1]=x0[1]; bv[2]=x0[2]; bv[3]=x0[3];
        bv[4]=x1[0]; bv[5]=x1[1]; bv[6]=x1[2]; bv[7]=x1[3];
    } else {
        #pragma unroll
        for (int i = 0; i < 8; ++i) bv[i] = 0.0f;
    }

    // C layout: frag-col = l16 -> actual cols l16*8+0..7 contiguous -> 16B stores
    const int rbase = m0 + wave * 16 + quad * 4;
    #pragma unroll
    for (int r = 0; r < 4; ++r) {
        int rr = rbase + r;
        if (rr < M) {
            half8v o;
            #pragma unroll
            for (int nt = 0; nt < 8; ++nt) o[nt] = (_Float16)(acc[nt][r] + bv[nt]);
            *(half8v*)&U[(long)rr * 128 + l16 * 8] = o;
        }
    }
}

// ---- Kernel 3: gather + relu-dot, 8 lanes/edge, ILP-2 (two edges per thread) ----
// Latency-bound gather: issue all 8 gather loads (2 edges x 2 sides x 32B) before
// any compute -> 2x memory-level parallelism per wave vs ILP-1. VGPR ~55 (<=64
// keeps 8 waves/SIMD). Nontemporal on row/col/out keeps L2 for u_s/u_c gathers.
__global__ __launch_bounds__(256) void edge_kernel(
    const int* __restrict__ row, const int* __restrict__ col,
    const _Float16* __restrict__ us, const _Float16* __restrict__ uc,
    const _Float16* __restrict__ w2h, const float* __restrict__ b2,
    float* __restrict__ out, int E)
{
    const int t = threadIdx.x;
    const int sub = t & 7;
    long e0 = (long)blockIdx.x * 64 + (t >> 3);   // edges e0 and e0+32
    long e1 = e0 + 32;
    if (e0 >= E) return;
    const bool v1 = e1 < (long)E;
    long eb = v1 ? e1 : e0;

    int r0 = __builtin_nontemporal_load(&row[e0]);
    int c0 = __builtin_nontemporal_load(&col[e0]);
    int r1 = __builtin_nontemporal_load(&row[eb]);
    int c1 = __builtin_nontemporal_load(&col[eb]);

    const uint4* pa0 = (const uint4*)(us  + (long)r0 * 128 + sub * 16);
    const uint4* pb0 = (const uint4*)(uc  + (long)c0 * 128 + sub * 16);
    const uint4* pa1 = (const uint4*)(us  + (long)r1 * 128 + sub * 16);
    const uint4* pb1 = (const uint4*)(uc  + (long)c1 * 128 + sub * 16);
    const uint4* pw  = (const uint4*)(w2h + sub * 16);

    // Issue all gathers up-front (independent addresses -> 8 loads in flight/lane).
    uint4 a00 = pa0[0], a01 = pa0[1];
    uint4 b00 = pb0[0], b01 = pb0[1];
    uint4 a10 = pa1[0], a11 = pa1[1];
    uint4 b10 = pb1[0], b11 = pb1[1];
    uint4 w0  = pw[0],  w1  = pw[1];

    half2v A0[8], B0[8], A1[8], B1[8], W[8];
    *(uint4*)&A0[0] = a00; *(uint4*)&A0[4] = a01;
    *(uint4*)&B0[0] = b00; *(uint4*)&B0[4] = b01;
    *(uint4*)&A1[0] = a10; *(uint4*)&A1[4] = a11;
    *(uint4*)&B1[0] = b10; *(uint4*)&B1[4] = b11;
    *(uint4*)&W[0]  = w0;  *(uint4*)&W[4]  = w1;

    const half2v zero = {(_Float16)0, (_Float16)0};
    float s0 = 0.0f, s1 = 0.0f;
    #pragma unroll
    for (int i = 0; i < 8; ++i) {
        half2v h0 = A0[i] + B0[i];                    // v_pk_add_f16
        half2v h1 = A1[i] + B1[i];
        h0 = __builtin_elementwise_max(h0, zero);     // v_pk_max_f16
        h1 = __builtin_elementwise_max(h1, zero);
        s0 += (float)h0[0] * (float)W[i][0];
        s0 += (float)h0[1] * (float)W[i][1];
        s1 += (float)h1[0] * (float)W[i][0];
        s1 += (float)h1[1] * (float)W[i][1];
    }
    s0 += __shfl_xor(s0, 1);
    s1 += __shfl_xor(s1, 1);
    s0 += __shfl_xor(s0, 2);
    s1 += __shfl_xor(s1, 2);
    s0 += __shfl_xor(s0, 4);
    s1 += __shfl_xor(s1, 4);
    if (sub == 0) {
        float bb = b2[0];
        __builtin_nontemporal_store(s0 + bb, &out[e0]);
        if (v1) __builtin_nontemporal_store(s1 + bb, &out[e1]);
    }
}

extern "C" void kernel_launch(void* const* d_in, const int* in_sizes, int n_in,
                              void* d_out, int out_size, void* d_ws, size_t ws_size,
                              hipStream_t stream) {
    const float* zs  = (const float*)d_in[0];
    const float* zc  = (const float*)d_in[1];
    const int*   row = (const int*)d_in[2];
    const int*   col = (const int*)d_in[3];
    const float* W1  = (const float*)d_in[4];
    const float* b1  = (const float*)d_in[5];
    const float* W2  = (const float*)d_in[6];
    const float* b2  = (const float*)d_in[7];
    float* out = (float*)d_out;

    const int Ms = in_sizes[0] / 128;   // 100000
    const int Mc = in_sizes[1] / 128;   // 20000
    const int E  = in_sizes[2];         // 1000000

    _Float16* Wt  = (_Float16*)d_ws;                           // 2*128*128 f16 = 64 KiB
    _Float16* w2h = (_Float16*)((char*)d_ws + 65536);          // 128 f16
    _Float16* us  = (_Float16*)((char*)d_ws + 65536 + 256);    // Ms*128 f16
    _Float16* uc  = us + (size_t)Ms * 128;                     // Mc*128 f16

    const int nbs = (Ms + 63) / 64, nbc = (Mc + 63) / 64;

    conv_w<<<9, 256, 0, stream>>>(W1, W2, Wt, w2h);
    gemm_u<<<nbs + nbc, 256, 0, stream>>>(zs, zc, Wt, b1, us, uc, Ms, Mc, nbs);
    edge_kernel<<<(E + 63) / 64, 256, 0, stream>>>(row, col, us, uc, w2h, b2, out, E);
}